// Round 1
// baseline (3652.568 us; speedup 1.0000x reference)
//
#include <hip/hip_runtime.h>
#include <stdint.h>

#define B_    2048
#define N_    64
#define C_    256
#define C2_   128
#define H_    8
#define NW_   64
#define NPOS  225   // 15*15

// Module-scope scratch (graph-capture safe; rewritten by k_prep every launch).
__device__ float g_bias[H_ * N_ * N_];   // 16*sigmoid(cpb bias), [h][i][j]
__device__ float g_scale[H_];            // exp(min(logit_scale, log 100))

__device__ __forceinline__ float b2f(unsigned short u) {
  return __uint_as_float(((unsigned int)u) << 16);
}
__device__ __forceinline__ unsigned short f2b(float f) {
  unsigned int u = __float_as_uint(f);
  u += 0x7fffu + ((u >> 16) & 1u);    // RNE
  return (unsigned short)(u >> 16);
}
__device__ __forceinline__ float rdlane(float v, int l) {
  return __uint_as_float(__builtin_amdgcn_readlane(__float_as_uint(v), l));
}

// --- K0: CPB-MLP bias table + per-head scale (tiny, one block) ---------------
__global__ __launch_bounds__(256) void k_prep(
    const float* __restrict__ tbl, const float* __restrict__ w1,
    const float* __restrict__ b1, const float* __restrict__ w2,
    const float* __restrict__ ls, const int* __restrict__ rpi) {
  __shared__ float t8[NPOS][H_];
  const int t = threadIdx.x;
  if (t < NPOS) {
    float a0 = tbl[2 * t], a1 = tbl[2 * t + 1];
    float acc[H_];
#pragma unroll
    for (int h = 0; h < H_; ++h) acc[h] = 0.f;
    for (int j = 0; j < 128; ++j) {
      float hid = fmaxf(a0 * w1[j] + a1 * w1[128 + j] + b1[j], 0.f);
#pragma unroll
      for (int h = 0; h < H_; ++h) acc[h] += hid * w2[j * H_ + h];
    }
#pragma unroll
    for (int h = 0; h < H_; ++h) t8[t][h] = acc[h];
  }
  if (t < H_) g_scale[t] = __expf(fminf(ls[t], 4.6051702f));
  __syncthreads();
  for (int e = t; e < H_ * N_ * N_; e += 256) {
    int h = e >> 12, ij = e & 4095;
    float v = t8[rpi[ij]][h];
    g_bias[e] = 16.f / (1.f + __expf(-v));
  }
}

// --- K1: fused window-attention block (1 block = 1 window) -------------------
// LDS strides: 266 bf16 elems/row = 133 dwords -> bank = (5*row + col) % 32,
// conflict-free for per-lane-row access. Weights read via wave-uniform
// addresses (readfirstlane on wave id) so the compiler emits s_load (SMEM).
__global__ __launch_bounds__(256) void k_main(
    const float* __restrict__ x, const float* __restrict__ mask,
    const float* __restrict__ qw, const float* __restrict__ qb,
    const float* __restrict__ kw, const float* __restrict__ kb,
    const float* __restrict__ vw, const float* __restrict__ vb,
    const float* __restrict__ pw, const float* __restrict__ pb,
    float* __restrict__ out) {
  __shared__ unsigned short xs[N_][266];  // x (bf16), later attn-out
  __shared__ unsigned short qs[N_][266];  // qn * scale[h] (bf16)
  __shared__ unsigned short ks[N_][266];  // kn (bf16)
  __shared__ unsigned short vs[N_][266];  // v (bf16)
  __shared__ float S[N_][67];             // per-head scores / probs
  __shared__ float ps[4][N_];             // softmax partial sums

  const int t = threadIdx.x;
  const int lane = t & 63;
  const int wu = __builtin_amdgcn_readfirstlane(t >> 6);  // wave id, uniform
  const int b = blockIdx.x;

  // P0: stage x -> bf16 LDS
  {
    const float4* xg = (const float4*)(x + (size_t)b * (N_ * C_));
    for (int e = t; e < (N_ * C_) / 4; e += 256) {
      float4 v = xg[e];
      int i = e >> 6, c = (e & 63) << 2;
      xs[i][c]     = f2b(v.x);
      xs[i][c + 1] = f2b(v.y);
      xs[i][c + 2] = f2b(v.z);
      xs[i][c + 3] = f2b(v.w);
    }
  }
  __syncthreads();

  // P1: dual-branch residual projections q,k,v (+ l2norm for q,k; scale on q)
  for (int pj = 0; pj < 3; ++pj) {
    const float* w  = pj == 0 ? qw : (pj == 1 ? kw : vw);
    const float* bi = pj == 0 ? qb : (pj == 1 ? kb : vb);
    unsigned short (*dst)[266] = pj == 0 ? qs : (pj == 1 ? ks : vs);
    for (int hc = 0; hc < 2; ++hc) {
      const int h  = 2 * wu + hc;     // uniform per wave
      const int jb = h << 5;          // global channel base
      const int s  = jb >> 7;         // half
      const int jl = jb & 127;        // col within half
      const float* wp = w + s * (C2_ * C2_) + jl;
      const float* bp = bi + s * C2_ + jl;
      float acc[32];
#pragma unroll
      for (int d = 0; d < 32; ++d) acc[d] = bp[d];
      const int so = s << 7;
#pragma unroll 2
      for (int c = 0; c < C2_; ++c) {
        float xv = b2f(xs[lane][so + c]);        // per-lane row, bank-free
        const float* wr = wp + c * C2_;          // uniform -> s_load
#pragma unroll
        for (int d = 0; d < 32; ++d) acc[d] = fmaf(xv, wr[d], acc[d]);
      }
#pragma unroll
      for (int d = 0; d < 32; ++d) acc[d] += b2f(xs[lane][jb + d]);  // residual
      if (pj < 2) {                              // l2norm over head dim
        float ss = 0.f;
#pragma unroll
        for (int d = 0; d < 32; ++d) ss += acc[d] * acc[d];
        float r = 1.0f / fmaxf(sqrtf(ss), 1e-12f);
        if (pj == 0) r *= g_scale[h];            // fold cosine-attn scale into qn
#pragma unroll
        for (int d = 0; d < 32; ++d) acc[d] *= r;
      }
#pragma unroll
      for (int d = 0; d < 32; ++d) dst[lane][jb + d] = f2b(acc[d]);
    }
  }
  __syncthreads();

  // P2: per-head attention. Scores/PV use v_readlane broadcasts from per-lane
  // register rows (no LDS broadcast storms).
  const float* mrow = mask + (size_t)(b & (NW_ - 1)) * (N_ * N_);
  for (int h = 0; h < H_; ++h) {
    float qr[32], kr[32];
#pragma unroll
    for (int d = 0; d < 32; ++d) qr[d] = b2f(qs[lane][(h << 5) + d]);
#pragma unroll
    for (int d = 0; d < 32; ++d) kr[d] = b2f(ks[lane][(h << 5) + d]);
    const float* bh = g_bias + (h << 12);
    // scores: wave wu owns rows [16wu, 16wu+16); S[i][lane]
#pragma unroll 2
    for (int ii = 0; ii < 16; ++ii) {
      int i = (wu << 4) + ii;
      float a = 0.f;
#pragma unroll
      for (int d = 0; d < 32; ++d) a = fmaf(rdlane(qr[d], i), kr[d], a);
      S[i][lane] = a + bh[(i << 6) + lane] + mrow[(i << 6) + lane];
    }
    __syncthreads();
    // softmax, no max-subtraction (|S| <= ~31, exp fits fp32 easily)
    float e[16], pq = 0.f;
#pragma unroll
    for (int jj = 0; jj < 16; ++jj) {
      e[jj] = __expf(S[lane][(wu << 4) + jj]);
      pq += e[jj];
    }
    ps[wu][lane] = pq;
    __syncthreads();
    {
      float r = 1.0f / (ps[0][lane] + ps[1][lane] + ps[2][lane] + ps[3][lane]);
#pragma unroll
      for (int jj = 0; jj < 16; ++jj) S[lane][(wu << 4) + jj] = e[jj] * r;
    }
    __syncthreads();
    // PV: lane = out row i, wave wu owns 8-channel slice of the head
    float vr[8], o8[8];
#pragma unroll
    for (int d = 0; d < 8; ++d) {
      vr[d] = b2f(vs[lane][(h << 5) + (wu << 3) + d]);
      o8[d] = 0.f;
    }
#pragma unroll 4
    for (int j = 0; j < 64; ++j) {
      float p = S[lane][j];            // per-lane row, bank-free
#pragma unroll
      for (int d = 0; d < 8; ++d) o8[d] = fmaf(p, rdlane(vr[d], j), o8[d]);
    }
#pragma unroll
    for (int d = 0; d < 8; ++d)
      xs[lane][(h << 5) + (wu << 3) + d] = f2b(o8[d]);   // attn-out reuses xs
    __syncthreads();
  }

  // P3: output projection y = ob @ pw + pb (no residual, no norm)
  for (int hc = 0; hc < 2; ++hc) {
    const int h  = 2 * wu + hc;
    const int jb = h << 5;
    const int s  = jb >> 7;
    const int jl = jb & 127;
    const float* wp = pw + s * (C2_ * C2_) + jl;
    float acc[32];
#pragma unroll
    for (int d = 0; d < 32; ++d) acc[d] = pb[s * C2_ + jl + d];
    const int so = s << 7;
#pragma unroll 2
    for (int c = 0; c < C2_; ++c) {
      float xv = b2f(xs[lane][so + c]);
      const float* wr = wp + c * C2_;
#pragma unroll
      for (int d = 0; d < 32; ++d) acc[d] = fmaf(xv, wr[d], acc[d]);
    }
    float* yp = out + ((size_t)b * N_ + lane) * C_ + jb;
#pragma unroll
    for (int d4 = 0; d4 < 8; ++d4) {
      float4 o;
      o.x = acc[4 * d4];     o.y = acc[4 * d4 + 1];
      o.z = acc[4 * d4 + 2]; o.w = acc[4 * d4 + 3];
      ((float4*)yp)[d4] = o;
    }
  }
}

extern "C" void kernel_launch(void* const* d_in, const int* in_sizes, int n_in,
                              void* d_out, int out_size, void* d_ws, size_t ws_size,
                              hipStream_t stream) {
  const float* x    = (const float*)d_in[0];
  const float* mask = (const float*)d_in[1];
  const float* qw   = (const float*)d_in[2];
  const float* qb   = (const float*)d_in[3];
  const float* kw   = (const float*)d_in[4];
  const float* kb   = (const float*)d_in[5];
  const float* vw   = (const float*)d_in[6];
  const float* vb   = (const float*)d_in[7];
  const float* pw   = (const float*)d_in[8];
  const float* pb   = (const float*)d_in[9];
  const float* w1   = (const float*)d_in[10];
  const float* b1   = (const float*)d_in[11];
  const float* w2   = (const float*)d_in[12];
  const float* ls   = (const float*)d_in[13];
  const float* tbl  = (const float*)d_in[14];
  const int*   rpi  = (const int*)d_in[15];
  float* out = (float*)d_out;

  k_prep<<<1, 256, 0, stream>>>(tbl, w1, b1, w2, ls, rpi);
  k_main<<<B_, 256, 0, stream>>>(x, mask, qw, qb, kw, kb, vw, vb, pw, pb, out);
}

// Round 2
// 515.422 us; speedup vs baseline: 7.0866x; 7.0866x over previous
//
#include <hip/hip_runtime.h>
#include <stdint.h>

#define B_    2048
#define N_    64
#define C_    256
#define C2_   128
#define H_    8
#define NW_   64
#define NPOS  225   // 15*15

typedef __attribute__((ext_vector_type(8))) short short8;
typedef __attribute__((ext_vector_type(4))) float float4v;

// Module-scope scratch (graph-safe; rewritten by prep kernels every launch).
__device__ float g_scale[H_];                    // exp(min(logit_scale, log100))
__device__ float g_t8[NPOS][H_];                 // CPB-MLP table
__device__ float g_sb[NW_ * H_ * N_ * N_];       // 16*sigmoid(bias)+mask (fp32, 8MB)
__device__ unsigned short g_wt[4][2][C2_][C2_];  // bf16 W^T: [proj][half][d][c]

__device__ __forceinline__ float b2f(unsigned short u) {
  return __uint_as_float(((unsigned int)u) << 16);
}
__device__ __forceinline__ unsigned short f2b(float f) {
  unsigned int u = __float_as_uint(f);
  u += 0x7fffu + ((u >> 16) & 1u);    // RNE
  return (unsigned short)(u >> 16);
}

// --- prep 1: CPB-MLP table + per-head scale (1 block) ------------------------
__global__ __launch_bounds__(256) void k_prep1(
    const float* __restrict__ tbl, const float* __restrict__ w1,
    const float* __restrict__ b1, const float* __restrict__ w2,
    const float* __restrict__ ls) {
  const int t = threadIdx.x;
  if (t < NPOS) {
    float a0 = tbl[2 * t], a1 = tbl[2 * t + 1];
    float acc[H_];
#pragma unroll
    for (int h = 0; h < H_; ++h) acc[h] = 0.f;
    for (int j = 0; j < 128; ++j) {
      float hid = fmaxf(a0 * w1[j] + a1 * w1[128 + j] + b1[j], 0.f);
#pragma unroll
      for (int h = 0; h < H_; ++h) acc[h] += hid * w2[j * H_ + h];
    }
#pragma unroll
    for (int h = 0; h < H_; ++h) g_t8[t][h] = acc[h];
  }
  if (t < H_) g_scale[t] = __expf(fminf(ls[t], 4.6051702f));
}

// --- prep 2: combined 16*sigmoid(bias)+mask table (2048 blocks) --------------
__global__ __launch_bounds__(256) void k_prep2(
    const float* __restrict__ mask, const int* __restrict__ rpi) {
  const int base = blockIdx.x * 1024;
#pragma unroll
  for (int it = 0; it < 4; ++it) {
    int idx = base + it * 256 + threadIdx.x;     // [0, 2M)
    int w  = idx >> 15;
    int e  = idx & 32767;
    int h  = e >> 12;
    int ij = e & 4095;
    float v = g_t8[rpi[ij]][h];
    g_sb[idx] = 16.f / (1.f + __expf(-v)) + mask[w * 4096 + ij];
  }
}

// --- prep 3: weights -> bf16 transposed (8 blocks: p*2+s) --------------------
__global__ __launch_bounds__(256) void k_prepw(
    const float* __restrict__ qw, const float* __restrict__ kw,
    const float* __restrict__ vw, const float* __restrict__ pw) {
  const int p = blockIdx.x >> 1, s = blockIdx.x & 1;
  const float* src = (p == 0 ? qw : p == 1 ? kw : p == 2 ? vw : pw) + s * (C2_ * C2_);
#pragma unroll
  for (int it = 0; it < 64; ++it) {
    int e = it * 256 + threadIdx.x;   // [0, 16384): e = c*128 + d
    int c = e >> 7, d = e & 127;
    g_wt[p][s][d][c] = f2b(src[e]);   // coalesced read, scattered u16 write (L2)
  }
}

// --- main: fully fused window block, MFMA throughout (1 block = 1 window) ----
// LDS row strides: xs/qs/ks 264 bf16 (528 B, 16B-mult, bank-shift 4/row);
// vt/pl 72 bf16 (144 B). All short8 (b128) accesses 16B-aligned.
__global__ __launch_bounds__(256) void k_main(
    const float* __restrict__ x, float* __restrict__ out,
    const float* __restrict__ qb, const float* __restrict__ kb,
    const float* __restrict__ vb, const float* __restrict__ pb) {
  __shared__ __align__(16) unsigned short xs[N_ * 264];   // x, later attn-out
  __shared__ __align__(16) unsigned short qs[N_ * 264];   // qn*scale
  __shared__ __align__(16) unsigned short ks[N_ * 264];   // kn
  __shared__ __align__(16) unsigned short vt[C_ * 72];    // v transposed [chan][tok]
  __shared__ __align__(16) unsigned short pl[2][N_ * 72]; // probs (dbuf by head parity)

  const int t    = threadIdx.x;
  const int lane = t & 63;
  const int w    = __builtin_amdgcn_readfirstlane(t >> 6);
  const int b    = blockIdx.x;
  const int l15  = lane & 15;
  const int qd   = lane >> 4;         // quad 0..3
  const int jl   = 32 * w;            // this wave's col-slice base within a half

  // P0: stage x -> bf16 LDS
  {
    const float4* xg = (const float4*)(x + (size_t)b * (N_ * C_));
#pragma unroll
    for (int it = 0; it < 16; ++it) {
      int e = t + 256 * it;
      int row = e >> 6, c4 = (e & 63) << 2;
      float4 v = xg[e];
      uint2 pk;
      pk.x = ((unsigned)f2b(v.y) << 16) | f2b(v.x);
      pk.y = ((unsigned)f2b(v.w) << 16) | f2b(v.z);
      *(uint2*)&xs[row * 264 + c4] = pk;
    }
  }
  __syncthreads();

  const float scl0 = g_scale[w], scl1 = g_scale[4 + w];

  // P1: q,k,v dual-branch residual projections (+ l2norm, q-scale), MFMA
  for (int pj = 0; pj < 3; ++pj) {
    const float* bi = pj == 0 ? qb : (pj == 1 ? kb : vb);
#pragma unroll
    for (int s = 0; s < 2; ++s) {
      float4v acc[4][2];
      float b0 = bi[s * C2_ + jl + l15], b1 = bi[s * C2_ + jl + 16 + l15];
#pragma unroll
      for (int mt = 0; mt < 4; ++mt) {
        acc[mt][0] = float4v{b0, b0, b0, b0};
        acc[mt][1] = float4v{b1, b1, b1, b1};
      }
      const unsigned short* wt = &g_wt[pj][s][0][0];
#pragma unroll
      for (int kc = 0; kc < 4; ++kc) {
        int ko = kc * 32 + qd * 8;
        short8 a[4], bf[2];
#pragma unroll
        for (int mt = 0; mt < 4; ++mt)
          a[mt] = *(const short8*)&xs[(mt * 16 + l15) * 264 + s * 128 + ko];
        bf[0] = *(const short8*)&wt[(jl + l15) * C2_ + ko];
        bf[1] = *(const short8*)&wt[(jl + 16 + l15) * C2_ + ko];
#pragma unroll
        for (int mt = 0; mt < 4; ++mt)
#pragma unroll
          for (int nt = 0; nt < 2; ++nt)
            acc[mt][nt] = __builtin_amdgcn_mfma_f32_16x16x32_bf16(
                a[mt], bf[nt], acc[mt][nt], 0, 0, 0);
      }
      // epilogue: +residual, l2norm (q,k), write to LDS
      unsigned short* dst = pj == 0 ? qs : ks;
#pragma unroll
      for (int mt = 0; mt < 4; ++mt) {
        int row0 = mt * 16 + qd * 4;
        float vv[2][4];
#pragma unroll
        for (int nt = 0; nt < 2; ++nt)
#pragma unroll
          for (int r = 0; r < 4; ++r)
            vv[nt][r] = acc[mt][nt][r] +
                        b2f(xs[(row0 + r) * 264 + s * 128 + jl + nt * 16 + l15]);
        if (pj < 2) {
          float ss[4];
#pragma unroll
          for (int r = 0; r < 4; ++r) ss[r] = vv[0][r] * vv[0][r] + vv[1][r] * vv[1][r];
#pragma unroll
          for (int m = 1; m < 16; m <<= 1)
#pragma unroll
            for (int r = 0; r < 4; ++r) ss[r] += __shfl_xor(ss[r], m, 64);
#pragma unroll
          for (int r = 0; r < 4; ++r) {
            float rn = 1.0f / fmaxf(sqrtf(ss[r]), 1e-12f);
            if (pj == 0) rn *= (s ? scl1 : scl0);
            vv[0][r] *= rn;
            vv[1][r] *= rn;
          }
#pragma unroll
          for (int nt = 0; nt < 2; ++nt)
#pragma unroll
            for (int r = 0; r < 4; ++r)
              dst[(row0 + r) * 264 + s * 128 + jl + nt * 16 + l15] = f2b(vv[nt][r]);
        } else {
          // v -> transposed [chan][token]
#pragma unroll
          for (int nt = 0; nt < 2; ++nt)
#pragma unroll
            for (int r = 0; r < 4; ++r)
              vt[(s * 128 + jl + nt * 16 + l15) * 72 + row0 + r] = f2b(vv[nt][r]);
        }
      }
    }
  }
  __syncthreads();

  // P2: attention — no barriers inside (wave w owns rows [16w,16w+16))
  const float* sb = g_sb + (size_t)(b & 63) * (H_ * N_ * N_);
#pragma unroll 2
  for (int h = 0; h < H_; ++h) {
    const float* sbh = sb + h * 4096;
    unsigned short* plh = pl[h & 1];
    // scores: C-init = bias+mask, one MFMA per 16x16 tile (K = hd = 32)
    short8 aq = *(const short8*)&qs[(16 * w + l15) * 264 + h * 32 + qd * 8];
    float4v sacc[4];
#pragma unroll
    for (int nt = 0; nt < 4; ++nt) {
      float4v c;
#pragma unroll
      for (int r = 0; r < 4; ++r)
        c[r] = sbh[(16 * w + qd * 4 + r) * 64 + nt * 16 + l15];
      short8 bk = *(const short8*)&ks[(nt * 16 + l15) * 264 + h * 32 + qd * 8];
      sacc[nt] = __builtin_amdgcn_mfma_f32_16x16x32_bf16(aq, bk, c, 0, 0, 0);
    }
    // softmax (no max-sub: |S| <= ~31): exp, row-sum via 16-lane shuffle
    float e[4][4], rs[4];
#pragma unroll
    for (int r = 0; r < 4; ++r) rs[r] = 0.f;
#pragma unroll
    for (int nt = 0; nt < 4; ++nt)
#pragma unroll
      for (int r = 0; r < 4; ++r) {
        e[nt][r] = __expf(sacc[nt][r]);
        rs[r] += e[nt][r];
      }
#pragma unroll
    for (int m = 1; m < 16; m <<= 1)
#pragma unroll
      for (int r = 0; r < 4; ++r) rs[r] += __shfl_xor(rs[r], m, 64);
    float rr[4];
#pragma unroll
    for (int r = 0; r < 4; ++r) rr[r] = 1.0f / rs[r];
    // write P (C-layout scatter; same-wave consumer below)
#pragma unroll
    for (int nt = 0; nt < 4; ++nt)
#pragma unroll
      for (int r = 0; r < 4; ++r)
        plh[(16 * w + qd * 4 + r) * 72 + nt * 16 + l15] = f2b(e[nt][r] * rr[r]);
    // PV: O = P @ V  (A from pl, B from vt, both contiguous b128)
    float4v oacc[2];
    oacc[0] = float4v{0, 0, 0, 0};
    oacc[1] = float4v{0, 0, 0, 0};
#pragma unroll
    for (int kc = 0; kc < 2; ++kc) {
      short8 ap = *(const short8*)&plh[(16 * w + l15) * 72 + kc * 32 + qd * 8];
#pragma unroll
      for (int nt2 = 0; nt2 < 2; ++nt2) {
        short8 bv = *(const short8*)&vt[(h * 32 + nt2 * 16 + l15) * 72 + kc * 32 + qd * 8];
        oacc[nt2] = __builtin_amdgcn_mfma_f32_16x16x32_bf16(ap, bv, oacc[nt2], 0, 0, 0);
      }
    }
    // O -> xs (overwrites dead x; wave-private rows)
#pragma unroll
    for (int nt2 = 0; nt2 < 2; ++nt2)
#pragma unroll
      for (int r = 0; r < 4; ++r)
        xs[(16 * w + qd * 4 + r) * 264 + h * 32 + nt2 * 16 + l15] = f2b(oacc[nt2][r]);
  }
  __syncthreads();

  // P3: output projection (no residual, no norm), MFMA, fp32 stores
#pragma unroll
  for (int s = 0; s < 2; ++s) {
    float4v acc[4][2];
    float b0 = pb[s * C2_ + jl + l15], b1 = pb[s * C2_ + jl + 16 + l15];
#pragma unroll
    for (int mt = 0; mt < 4; ++mt) {
      acc[mt][0] = float4v{b0, b0, b0, b0};
      acc[mt][1] = float4v{b1, b1, b1, b1};
    }
    const unsigned short* wt = &g_wt[3][s][0][0];
#pragma unroll
    for (int kc = 0; kc < 4; ++kc) {
      int ko = kc * 32 + qd * 8;
      short8 a[4], bf[2];
#pragma unroll
      for (int mt = 0; mt < 4; ++mt)
        a[mt] = *(const short8*)&xs[(mt * 16 + l15) * 264 + s * 128 + ko];
      bf[0] = *(const short8*)&wt[(jl + l15) * C2_ + ko];
      bf[1] = *(const short8*)&wt[(jl + 16 + l15) * C2_ + ko];
#pragma unroll
      for (int mt = 0; mt < 4; ++mt)
#pragma unroll
        for (int nt = 0; nt < 2; ++nt)
          acc[mt][nt] = __builtin_amdgcn_mfma_f32_16x16x32_bf16(
              a[mt], bf[nt], acc[mt][nt], 0, 0, 0);
    }
#pragma unroll
    for (int mt = 0; mt < 4; ++mt)
#pragma unroll
      for (int nt = 0; nt < 2; ++nt)
#pragma unroll
        for (int r = 0; r < 4; ++r)
          out[((size_t)b * N_ + mt * 16 + qd * 4 + r) * C_ +
              s * 128 + jl + nt * 16 + l15] = acc[mt][nt][r];
  }
}

extern "C" void kernel_launch(void* const* d_in, const int* in_sizes, int n_in,
                              void* d_out, int out_size, void* d_ws, size_t ws_size,
                              hipStream_t stream) {
  const float* x    = (const float*)d_in[0];
  const float* mask = (const float*)d_in[1];
  const float* qw   = (const float*)d_in[2];
  const float* qb   = (const float*)d_in[3];
  const float* kw   = (const float*)d_in[4];
  const float* kb   = (const float*)d_in[5];
  const float* vw   = (const float*)d_in[6];
  const float* vb   = (const float*)d_in[7];
  const float* pw   = (const float*)d_in[8];
  const float* pb   = (const float*)d_in[9];
  const float* w1   = (const float*)d_in[10];
  const float* b1   = (const float*)d_in[11];
  const float* w2   = (const float*)d_in[12];
  const float* ls   = (const float*)d_in[13];
  const float* tbl  = (const float*)d_in[14];
  const int*   rpi  = (const int*)d_in[15];
  float* out = (float*)d_out;

  k_prep1<<<1, 256, 0, stream>>>(tbl, w1, b1, w2, ls);
  k_prep2<<<2048, 256, 0, stream>>>(mask, rpi);
  k_prepw<<<8, 256, 0, stream>>>(qw, kw, vw, pw);
  k_main<<<B_, 256, 0, stream>>>(x, out, qb, kb, vb, pb);
}

// Round 3
// 416.971 us; speedup vs baseline: 8.7598x; 1.2361x over previous
//
#include <hip/hip_runtime.h>
#include <stdint.h>

#define B_    2048
#define N_    64
#define C_    256
#define C2_   128
#define H_    8
#define NW_   64
#define NPOS  225   // 15*15

typedef __attribute__((ext_vector_type(8))) short short8;
typedef __attribute__((ext_vector_type(4))) float float4v;

// Module-scope scratch (graph-safe; rewritten by prep kernels every launch).
__device__ float g_scale[H_];                    // exp(min(logit_scale, log100))
__device__ float g_t8[NPOS][H_];                 // CPB-MLP table
__device__ __align__(16) float g_sb[NW_ * H_ * N_ * N_];  // [w][h][col j][row i]
__device__ unsigned short g_wt[4][2][C2_][C2_];  // bf16 W^T: [proj][half][d][c]

__device__ __forceinline__ float b2f(unsigned short u) {
  return __uint_as_float(((unsigned int)u) << 16);
}
__device__ __forceinline__ unsigned short f2b(float f) {
  unsigned int u = __float_as_uint(f);
  u += 0x7fffu + ((u >> 16) & 1u);    // RNE
  return (unsigned short)(u >> 16);
}

// --- prep 1: CPB-MLP table + per-head scale (1 block, LDS-staged weights) ----
__global__ __launch_bounds__(256) void k_prep1(
    const float* __restrict__ tbl, const float* __restrict__ w1,
    const float* __restrict__ b1, const float* __restrict__ w2,
    const float* __restrict__ ls) {
  __shared__ float sw1[256], sb1[128], sw2[1024];
  const int t = threadIdx.x;
  sw1[t] = w1[t];
  if (t < 128) sb1[t] = b1[t];
#pragma unroll
  for (int it = 0; it < 4; ++it) sw2[it * 256 + t] = w2[it * 256 + t];
  __syncthreads();
  if (t < NPOS) {
    float a0 = tbl[2 * t], a1 = tbl[2 * t + 1];
    float acc[H_];
#pragma unroll
    for (int h = 0; h < H_; ++h) acc[h] = 0.f;
    for (int j = 0; j < 128; ++j) {
      float hid = fmaxf(a0 * sw1[j] + a1 * sw1[128 + j] + sb1[j], 0.f);
#pragma unroll
      for (int h = 0; h < H_; ++h) acc[h] += hid * sw2[j * H_ + h];
    }
#pragma unroll
    for (int h = 0; h < H_; ++h) g_t8[t][h] = acc[h];
  }
  if (t < H_) g_scale[t] = __expf(fminf(ls[t], 4.6051702f));
}

// --- prep 2: 16*sigmoid(bias)+mask, TRANSPOSED [w][h][col][row] --------------
__global__ __launch_bounds__(256) void k_prep2(
    const float* __restrict__ mask, const int* __restrict__ rpi) {
  const int base = blockIdx.x * 1024;
#pragma unroll
  for (int it = 0; it < 4; ++it) {
    int idx = base + it * 256 + threadIdx.x;     // [0, 2M)
    int i  = idx & 63;            // row
    int j  = (idx >> 6) & 63;     // col
    int h  = (idx >> 12) & 7;
    int wd = idx >> 15;
    float v = g_t8[rpi[i * 64 + j]][h];
    g_sb[idx] = 16.f / (1.f + __expf(-v)) + mask[wd * 4096 + i * 64 + j];
  }
}

// --- prep 3: weights -> bf16 transposed via LDS (coalesced both sides) -------
__global__ __launch_bounds__(256) void k_prepw(
    const float* __restrict__ qw, const float* __restrict__ kw,
    const float* __restrict__ vw, const float* __restrict__ pw) {
  __shared__ unsigned short lt[128 * 132];
  const int t = threadIdx.x;
  const int p = blockIdx.x >> 1, s = blockIdx.x & 1;
  const float* src = (p == 0 ? qw : p == 1 ? kw : p == 2 ? vw : pw) + s * (C2_ * C2_);
#pragma unroll
  for (int it = 0; it < 64; ++it) {
    int e = it * 256 + t;         // e = c*128 + d, coalesced read
    int c = e >> 7, d = e & 127;
    lt[d * 132 + c] = f2b(src[e]);
  }
  __syncthreads();
#pragma unroll
  for (int it = 0; it < 64; ++it) {
    int e = it * 256 + t;         // e = d*128 + c, coalesced write
    int d = e >> 7, c = e & 127;
    g_wt[p][s][d][c] = lt[d * 132 + c];
  }
}

// --- main: fused window block, 512 threads (8 waves), 3 barriers total -------
// Wave roles: P1/P3: (s = w>>2, 32-col slice jl = 32*(w&3)).
//             P2:   (rows 16*(w&3), heads [4*(w>>2), +4)), private pl region.
__global__ __launch_bounds__(512) void k_main(
    const float* __restrict__ x, float* __restrict__ out,
    const float* __restrict__ qb, const float* __restrict__ kb,
    const float* __restrict__ vb, const float* __restrict__ pb) {
  __shared__ __align__(16) unsigned short xs[N_ * 264];   // x, later attn-out
  __shared__ __align__(16) unsigned short qs[N_ * 264];   // qn*scale
  __shared__ __align__(16) unsigned short ks[N_ * 264];   // kn
  __shared__ __align__(16) unsigned short vt[C_ * 72];    // v^T [chan][tok]
  __shared__ __align__(16) unsigned short pl[8 * 16 * 72];// P, per-wave 16 rows

  const int t    = threadIdx.x;
  const int lane = t & 63;
  const int w    = __builtin_amdgcn_readfirstlane(t >> 6);
  const int b    = blockIdx.x;
  const int l15  = lane & 15;
  const int qd   = lane >> 4;

  // P0: stage x -> bf16 LDS
  {
    const float4* xg = (const float4*)(x + (size_t)b * (N_ * C_));
#pragma unroll
    for (int it = 0; it < 8; ++it) {
      int e = t + 512 * it;
      int row = e >> 6, c4 = (e & 63) << 2;
      float4 v = xg[e];
      uint2 pk;
      pk.x = ((unsigned)f2b(v.y) << 16) | f2b(v.x);
      pk.y = ((unsigned)f2b(v.w) << 16) | f2b(v.z);
      *(uint2*)&xs[row * 264 + c4] = pk;
    }
  }
  __syncthreads();

  // P1: q,k,v dual-branch residual projections (+ l2norm, q-scale), MFMA
  const int s1 = w >> 2;            // half
  const int jl = 32 * (w & 3);      // col base within half
  const float scl = g_scale[s1 * 4 + (w & 3)];
  for (int pj = 0; pj < 3; ++pj) {
    const float* bi = pj == 0 ? qb : (pj == 1 ? kb : vb);
    float4v acc[4][2];
    {
      float b0 = bi[s1 * C2_ + jl + l15], b1 = bi[s1 * C2_ + jl + 16 + l15];
#pragma unroll
      for (int mt = 0; mt < 4; ++mt) {
        acc[mt][0] = float4v{b0, b0, b0, b0};
        acc[mt][1] = float4v{b1, b1, b1, b1};
      }
    }
    const unsigned short* wt = &g_wt[pj][s1][0][0];
#pragma unroll
    for (int kc = 0; kc < 4; ++kc) {
      int ko = kc * 32 + qd * 8;
      short8 a[4], bf[2];
#pragma unroll
      for (int mt = 0; mt < 4; ++mt)
        a[mt] = *(const short8*)&xs[(mt * 16 + l15) * 264 + s1 * 128 + ko];
      bf[0] = *(const short8*)&wt[(jl + l15) * C2_ + ko];
      bf[1] = *(const short8*)&wt[(jl + 16 + l15) * C2_ + ko];
#pragma unroll
      for (int mt = 0; mt < 4; ++mt)
#pragma unroll
        for (int nt = 0; nt < 2; ++nt)
          acc[mt][nt] = __builtin_amdgcn_mfma_f32_16x16x32_bf16(
              a[mt], bf[nt], acc[mt][nt], 0, 0, 0);
    }
    // epilogue: +residual, l2norm (q,k), write to LDS
    unsigned short* dst = pj == 0 ? qs : ks;
#pragma unroll
    for (int mt = 0; mt < 4; ++mt) {
      int row0 = mt * 16 + qd * 4;
      float vv[2][4];
#pragma unroll
      for (int nt = 0; nt < 2; ++nt)
#pragma unroll
        for (int r = 0; r < 4; ++r)
          vv[nt][r] = acc[mt][nt][r] +
                      b2f(xs[(row0 + r) * 264 + s1 * 128 + jl + nt * 16 + l15]);
      if (pj < 2) {
        float ss[4];
#pragma unroll
        for (int r = 0; r < 4; ++r) ss[r] = vv[0][r] * vv[0][r] + vv[1][r] * vv[1][r];
#pragma unroll
        for (int m = 1; m < 16; m <<= 1)
#pragma unroll
          for (int r = 0; r < 4; ++r) ss[r] += __shfl_xor(ss[r], m, 64);
#pragma unroll
        for (int r = 0; r < 4; ++r) {
          float rn = 1.0f / fmaxf(sqrtf(ss[r]), 1e-12f);
          if (pj == 0) rn *= scl;
          vv[0][r] *= rn;
          vv[1][r] *= rn;
        }
#pragma unroll
        for (int nt = 0; nt < 2; ++nt)
#pragma unroll
          for (int r = 0; r < 4; ++r)
            dst[(row0 + r) * 264 + s1 * 128 + jl + nt * 16 + l15] = f2b(vv[nt][r]);
      } else {
        // v -> transposed [chan][token], packed 4-token (8B) stores
#pragma unroll
        for (int nt = 0; nt < 2; ++nt) {
          int chan = s1 * 128 + jl + nt * 16 + l15;
          uint2 pk;
          pk.x = ((unsigned)f2b(vv[nt][1]) << 16) | f2b(vv[nt][0]);
          pk.y = ((unsigned)f2b(vv[nt][3]) << 16) | f2b(vv[nt][2]);
          *(uint2*)&vt[chan * 72 + row0] = pk;
        }
      }
    }
  }
  __syncthreads();

  // P2: attention — zero barriers (wave-private rows/heads/pl region)
  const int wm = w & 3, wg = w >> 2;
  unsigned short* plw = pl + w * (16 * 72);
  const float* sbb = g_sb + (size_t)(b & 63) * (H_ * N_ * N_);
#pragma unroll
  for (int hh = 0; hh < 4; ++hh) {
    const int h = 4 * wg + hh;
    const float* sbh = sbb + h * 4096;
    // scores: C-init = bias+mask (transposed table -> float4), K=hd=32
    short8 aq = *(const short8*)&qs[(16 * wm + l15) * 264 + h * 32 + qd * 8];
    float4v sacc[4];
#pragma unroll
    for (int nt = 0; nt < 4; ++nt) {
      float4 cv = *(const float4*)&sbh[(nt * 16 + l15) * 64 + 16 * wm + qd * 4];
      float4v c = {cv.x, cv.y, cv.z, cv.w};
      short8 bk = *(const short8*)&ks[(nt * 16 + l15) * 264 + h * 32 + qd * 8];
      sacc[nt] = __builtin_amdgcn_mfma_f32_16x16x32_bf16(aq, bk, c, 0, 0, 0);
    }
    // softmax (no max-sub: |S| <= ~31)
    float e[4][4], rs[4];
#pragma unroll
    for (int r = 0; r < 4; ++r) rs[r] = 0.f;
#pragma unroll
    for (int nt = 0; nt < 4; ++nt)
#pragma unroll
      for (int r = 0; r < 4; ++r) {
        e[nt][r] = __expf(sacc[nt][r]);
        rs[r] += e[nt][r];
      }
#pragma unroll
    for (int m = 1; m < 16; m <<= 1)
#pragma unroll
      for (int r = 0; r < 4; ++r) rs[r] += __shfl_xor(rs[r], m, 64);
    float rr[4];
#pragma unroll
    for (int r = 0; r < 4; ++r) rr[r] = 1.0f / rs[r];
    // write P into wave-private pl region (local rows 0..15)
#pragma unroll
    for (int nt = 0; nt < 4; ++nt)
#pragma unroll
      for (int r = 0; r < 4; ++r)
        plw[(qd * 4 + r) * 72 + nt * 16 + l15] = f2b(e[nt][r] * rr[r]);
    // PV: O = P @ V (A from plw, B from vt, contiguous b128)
    float4v oacc[2];
    oacc[0] = float4v{0, 0, 0, 0};
    oacc[1] = float4v{0, 0, 0, 0};
#pragma unroll
    for (int kc = 0; kc < 2; ++kc) {
      short8 ap = *(const short8*)&plw[l15 * 72 + kc * 32 + qd * 8];
#pragma unroll
      for (int nt2 = 0; nt2 < 2; ++nt2) {
        short8 bv = *(const short8*)&vt[(h * 32 + nt2 * 16 + l15) * 72 + kc * 32 + qd * 8];
        oacc[nt2] = __builtin_amdgcn_mfma_f32_16x16x32_bf16(ap, bv, oacc[nt2], 0, 0, 0);
      }
    }
    // O -> xs rows [16wm..), chans [32h..): wave-unique region
#pragma unroll
    for (int nt2 = 0; nt2 < 2; ++nt2)
#pragma unroll
      for (int r = 0; r < 4; ++r)
        xs[(16 * wm + qd * 4 + r) * 264 + h * 32 + nt2 * 16 + l15] = f2b(oacc[nt2][r]);
  }
  __syncthreads();

  // P3: output projection (no residual/norm), MFMA, fp32 stores
  {
    float4v acc[4][2];
    float b0 = pb[s1 * C2_ + jl + l15], b1 = pb[s1 * C2_ + jl + 16 + l15];
#pragma unroll
    for (int mt = 0; mt < 4; ++mt) {
      acc[mt][0] = float4v{b0, b0, b0, b0};
      acc[mt][1] = float4v{b1, b1, b1, b1};
    }
    const unsigned short* wt = &g_wt[3][s1][0][0];
#pragma unroll
    for (int kc = 0; kc < 4; ++kc) {
      int ko = kc * 32 + qd * 8;
      short8 a[4], bf[2];
#pragma unroll
      for (int mt = 0; mt < 4; ++mt)
        a[mt] = *(const short8*)&xs[(mt * 16 + l15) * 264 + s1 * 128 + ko];
      bf[0] = *(const short8*)&wt[(jl + l15) * C2_ + ko];
      bf[1] = *(const short8*)&wt[(jl + 16 + l15) * C2_ + ko];
#pragma unroll
      for (int mt = 0; mt < 4; ++mt)
#pragma unroll
        for (int nt = 0; nt < 2; ++nt)
          acc[mt][nt] = __builtin_amdgcn_mfma_f32_16x16x32_bf16(
              a[mt], bf[nt], acc[mt][nt], 0, 0, 0);
    }
#pragma unroll
    for (int mt = 0; mt < 4; ++mt)
#pragma unroll
      for (int nt = 0; nt < 2; ++nt)
#pragma unroll
        for (int r = 0; r < 4; ++r)
          out[((size_t)b * N_ + mt * 16 + qd * 4 + r) * C_ +
              s1 * 128 + jl + nt * 16 + l15] = acc[mt][nt][r];
  }
}

extern "C" void kernel_launch(void* const* d_in, const int* in_sizes, int n_in,
                              void* d_out, int out_size, void* d_ws, size_t ws_size,
                              hipStream_t stream) {
  const float* x    = (const float*)d_in[0];
  const float* mask = (const float*)d_in[1];
  const float* qw   = (const float*)d_in[2];
  const float* qb   = (const float*)d_in[3];
  const float* kw   = (const float*)d_in[4];
  const float* kb   = (const float*)d_in[5];
  const float* vw   = (const float*)d_in[6];
  const float* vb   = (const float*)d_in[7];
  const float* pw   = (const float*)d_in[8];
  const float* pb   = (const float*)d_in[9];
  const float* w1   = (const float*)d_in[10];
  const float* b1   = (const float*)d_in[11];
  const float* w2   = (const float*)d_in[12];
  const float* ls   = (const float*)d_in[13];
  const float* tbl  = (const float*)d_in[14];
  const int*   rpi  = (const int*)d_in[15];
  float* out = (float*)d_out;

  k_prep1<<<1, 256, 0, stream>>>(tbl, w1, b1, w2, ls);
  k_prep2<<<2048, 256, 0, stream>>>(mask, rpi);
  k_prepw<<<8, 256, 0, stream>>>(qw, kw, vw, pw);
  k_main<<<B_, 512, 0, stream>>>(x, out, qb, kb, vb, pb);
}